// Round 3
// baseline (110954.663 us; speedup 1.0000x reference)
//
#include <hip/hip_runtime.h>
#include <hip/hip_bf16.h>

// R3: all-float32 (reference dtypes are jnp.float32; in_npz size confirms f32 staging).
// Persistent decoder: 128 blocks (1 per batch element) x 1024 threads.
// Prenet computed inline per step -> zero workspace usage (de-risks ws_size).

#define BB   128
#define TEN  512
#define HD   256
#define PREN 128
#define TDEC 200
#define RDM  400
#define G3   768

__device__ __forceinline__ float frcp(float x){ return __builtin_amdgcn_rcpf(x); }
// tanh = 1 - 2/(1+e^{2x}): saturates correctly for |x| large (exp->inf/0)
__device__ __forceinline__ float tanh_f(float x){ float e = __expf(2.f*x); return 1.f - 2.f*frcp(1.f + e); }
__device__ __forceinline__ float sig_f(float x){ return frcp(1.f + __expf(-x)); }

// in-block matvec: out[N] = W(NxK f32) @ x[K] (+bias, opt relu).
// TPR=K/32 threads per row; each covers 32 cols = 8 x float4; shfl reduce.
// Bank-stagger ce=(c+part)&7 keeps LDS x reads conflict-free.
template<int N, int K, bool TOG, bool RELU>
__device__ __forceinline__ void matvec(const float* __restrict__ W, const float* __restrict__ bias,
                                       const float* x, float* out, float* gout, int tid)
{
  constexpr int TPR = K / 32;
  constexpr int RPS = 1024 / TPR;
  const int part = tid & (TPR - 1);
  const int r0 = tid / TPR;
  #pragma unroll
  for (int s = 0; s < (N + RPS - 1) / RPS; ++s) {
    const int row = s * RPS + r0;
    if (row < N) {   // boundary lands on wave boundary for all instantiations used
      const float* wr = W + (size_t)row * K + part * 32;
      const float* xr = x + part * 32;
      float acc = 0.f;
      #pragma unroll
      for (int c = 0; c < 8; ++c) {
        const int ce = (c + part) & 7;
        const float4 w4 = *(const float4*)(wr + ce * 4);
        const float4 x4 = *(const float4*)(xr + ce * 4);
        acc = fmaf(w4.x, x4.x, acc); acc = fmaf(w4.y, x4.y, acc);
        acc = fmaf(w4.z, x4.z, acc); acc = fmaf(w4.w, x4.w, acc);
      }
      #pragma unroll
      for (int off = 1; off < TPR; off <<= 1) acc += __shfl_xor(acc, off, 64);
      if (part == 0) {
        float o = acc + (bias ? bias[row] : 0.f);
        if (RELU) o = fmaxf(o, 0.f);
        if (TOG) gout[row] = o; else out[row] = o;
      }
    }
  }
}

__global__ __launch_bounds__(1024) void decoder_kernel(
    const float* __restrict__ memf, const float* __restrict__ tgt,
    const float* pW1, const float* pb1, const float* pW2, const float* pb2,
    const float* aWih, const float* aWhh, const float* abih, const float* abhh,
    const float* qW, const float* vW, const float* projW,
    const float* g1Wih, const float* g1Whh, const float* g1bih, const float* g1bhh,
    const float* g2Wih, const float* g2Whh, const float* g2bih, const float* g2bhh,
    const float* specW, float* outp)
{
  const int b = blockIdx.x;
  const int tid = threadIdx.x;
  __shared__ __align__(16) float xrow[RDM], p1r[HD], p2r[PREN];
  __shared__ __align__(16) float h_att[HD], h1[HD], h2[HD], q2[HD], ov[HD], cat[2 * HD];
  __shared__ __align__(16) float giA[G3], gh[G3], ga[G3], gb[G3];
  __shared__ __align__(16) float sc[TEN], aw[TEN], vl[HD];
  __shared__ __align__(16) float ctxp[4][HD];
  __shared__ float red[20];

  if (tid < HD) { h_att[tid] = 0.f; h1[tid] = 0.f; h2[tid] = 0.f; vl[tid] = vW[tid]; }

  const size_t mb = (size_t)b * TEN * HD;
  float* tgt_out  = outp + (size_t)b * TDEC * RDM;
  float* attn_out = outp + (size_t)BB * TDEC * RDM + (size_t)b * TDEC * TEN;

  for (int t = 0; t < TDEC; ++t) {
    // teacher-forcing input row: zeros at t=0, else target[b] row t-1 (reshaped 200x400)
    if (tid < RDM) xrow[tid] = (t == 0) ? 0.f : tgt[(size_t)b * (TDEC * RDM) + (size_t)(t - 1) * RDM + tid];
    __syncthreads();
    // prenet layer 1: p1r = relu(pW1(256x400) @ xrow + pb1); 4 threads/row x 100 cols
    {
      const int part = tid & 3, row = tid >> 2;
      const float* wr = pW1 + (size_t)row * RDM + part * 100;
      const float* xr = xrow + part * 100;
      float acc = 0.f;
      #pragma unroll
      for (int c = 0; c < 25; ++c) {
        const float4 w4 = *(const float4*)(wr + c * 4);
        const float4 x4 = *(const float4*)(xr + c * 4);
        acc = fmaf(w4.x, x4.x, acc); acc = fmaf(w4.y, x4.y, acc);
        acc = fmaf(w4.z, x4.z, acc); acc = fmaf(w4.w, x4.w, acc);
      }
      acc += __shfl_xor(acc, 1, 64);
      acc += __shfl_xor(acc, 2, 64);
      if (part == 0) p1r[row] = fmaxf(acc + pb1[row], 0.f);
    }
    __syncthreads();
    // prenet layer 2: p2r = relu(pW2(128x256) @ p1r + pb2)
    matvec<PREN, HD, false, true>(pW2, pb2, p1r, p2r, nullptr, tid);
    __syncthreads();
    // attention GRU gates
    matvec<G3, PREN, false, false>(aWih, abih, p2r, giA, nullptr, tid);
    matvec<G3, HD,   false, false>(aWhh, abhh, h_att, gh, nullptr, tid);
    __syncthreads();
    if (tid < HD) {
      float r = sig_f(giA[tid] + gh[tid]);
      float z = sig_f(giA[HD + tid] + gh[HD + tid]);
      float n = tanh_f(giA[2 * HD + tid] + r * gh[2 * HD + tid]);
      float hq = (1.f - z) * n + z * h_att[tid];
      h_att[tid] = hq; cat[HD + tid] = hq;   // query into concat slot
    }
    __syncthreads();
    matvec<HD, HD, false, false>(qW, nullptr, h_att, q2, nullptr, tid);
    __syncthreads();
    // Bahdanau score: s[t'] = sum_h v[h]*tanh(q2[h] + mem[b,t',h]); 2 threads per t'
    {
      const int tt = tid >> 1, half = tid & 1;
      const float* mp = memf + mb + (size_t)tt * HD + half * 128;
      const float* qp = q2 + half * 128;
      const float* vp = vl + half * 128;
      float s = 0.f;
      #pragma unroll 8
      for (int c = 0; c < 32; ++c) {
        const float4 m4 = *(const float4*)(mp + c * 4);
        const float4 q4 = *(const float4*)(qp + c * 4);
        const float4 v4 = *(const float4*)(vp + c * 4);
        s = fmaf(v4.x, tanh_f(q4.x + m4.x), s);
        s = fmaf(v4.y, tanh_f(q4.y + m4.y), s);
        s = fmaf(v4.z, tanh_f(q4.z + m4.z), s);
        s = fmaf(v4.w, tanh_f(q4.w + m4.w), s);
      }
      s += __shfl_xor(s, 1, 64);
      if (half == 0) sc[tt] = s;
    }
    __syncthreads();
    // softmax over 512 + write attention weights (output 1)
    {
      const int w = tid >> 6, lane = tid & 63;
      if (tid < TEN) {
        float v = sc[tid];
        #pragma unroll
        for (int off = 32; off > 0; off >>= 1) v = fmaxf(v, __shfl_xor(v, off, 64));
        if (lane == 0) red[w] = v;
      }
      __syncthreads();
      if (tid == 0) {
        float m = red[0];
        #pragma unroll
        for (int i = 1; i < 8; ++i) m = fmaxf(m, red[i]);
        red[16] = m;
      }
      __syncthreads();
      const float m = red[16];
      if (tid < TEN) {
        float e = __expf(sc[tid] - m);
        aw[tid] = e;
        float v = e;
        #pragma unroll
        for (int off = 32; off > 0; off >>= 1) v += __shfl_xor(v, off, 64);
        if (lane == 0) red[w] = v;
      }
      __syncthreads();
      if (tid == 0) {
        float ssum = 0.f;
        #pragma unroll
        for (int i = 0; i < 8; ++i) ssum += red[i];
        red[17] = frcp(ssum);
      }
      __syncthreads();
      if (tid < TEN) {
        float a = aw[tid] * red[17];
        aw[tid] = a;
        attn_out[(size_t)t * TEN + tid] = a;
      }
    }
    __syncthreads();
    // ctx[h] = sum_t aw[t]*mem[b,t,h]; 4 t-groups x 256 h
    {
      const int g = tid >> 8, h = tid & 255;
      const float* mp = memf + mb + h;
      float a = 0.f;
      #pragma unroll 4
      for (int q = 0; q < 128; ++q) {
        const int tt = g * 128 + q;
        a = fmaf(aw[tt], mp[(size_t)tt * HD], a);
      }
      ctxp[g][h] = a;
    }
    __syncthreads();
    if (tid < HD) {
      cat[tid] = ctxp[0][tid] + ctxp[1][tid] + ctxp[2][tid] + ctxp[3][tid];
    }
    __syncthreads();
    matvec<HD, 2 * HD, false, false>(projW, nullptr, cat, ov, nullptr, tid);
    __syncthreads();
    matvec<G3, HD, false, false>(g1Wih, g1bih, ov, ga, nullptr, tid);
    matvec<G3, HD, false, false>(g1Whh, g1bhh, h1, gb, nullptr, tid);
    __syncthreads();
    if (tid < HD) {
      float r = sig_f(ga[tid] + gb[tid]);
      float z = sig_f(ga[HD + tid] + gb[HD + tid]);
      float n = tanh_f(ga[2 * HD + tid] + r * gb[2 * HD + tid]);
      h1[tid] = (1.f - z) * n + z * h1[tid] + ov[tid];   // residual
    }
    __syncthreads();
    matvec<G3, HD, false, false>(g2Wih, g2bih, h1, ga, nullptr, tid);
    matvec<G3, HD, false, false>(g2Whh, g2bhh, h2, gb, nullptr, tid);
    __syncthreads();
    if (tid < HD) {
      float r = sig_f(ga[tid] + gb[tid]);
      float z = sig_f(ga[HD + tid] + gb[HD + tid]);
      float n = tanh_f(ga[2 * HD + tid] + r * gb[2 * HD + tid]);
      h2[tid] = (1.f - z) * n + z * h2[tid] + h1[tid];   // residual
    }
    __syncthreads();
    // spectro projection straight to global (output 0)
    matvec<RDM, HD, true, false>(specW, nullptr, h2, nullptr, tgt_out + (size_t)t * RDM, tid);
    // loop-top sync (after xrow write) protects LDS reuse across iterations
  }
}

extern "C" void kernel_launch(void* const* d_in, const int* in_sizes, int n_in,
                              void* d_out, int out_size, void* d_ws, size_t ws_size,
                              hipStream_t stream)
{
  const float* memory = (const float*)d_in[0];
  const float* target = (const float*)d_in[1];
  const float* pW1  = (const float*)d_in[2];
  const float* pb1  = (const float*)d_in[3];
  const float* pW2  = (const float*)d_in[4];
  const float* pb2  = (const float*)d_in[5];
  const float* aWih = (const float*)d_in[6];
  const float* aWhh = (const float*)d_in[7];
  const float* abih = (const float*)d_in[8];
  const float* abhh = (const float*)d_in[9];
  const float* qW   = (const float*)d_in[10];
  const float* vW   = (const float*)d_in[11];
  const float* projW = (const float*)d_in[12];
  const float* g1Wih = (const float*)d_in[13];
  const float* g1Whh = (const float*)d_in[14];
  const float* g1bih = (const float*)d_in[15];
  const float* g1bhh = (const float*)d_in[16];
  const float* g2Wih = (const float*)d_in[17];
  const float* g2Whh = (const float*)d_in[18];
  const float* g2bih = (const float*)d_in[19];
  const float* g2bhh = (const float*)d_in[20];
  const float* specW = (const float*)d_in[21];

  decoder_kernel<<<BB, 1024, 0, stream>>>(memory, target,
      pW1, pb1, pW2, pb2,
      aWih, aWhh, abih, abhh, qW, vW, projW,
      g1Wih, g1Whh, g1bih, g1bhh, g2Wih, g2Whh, g2bih, g2bhh, specW,
      (float*)d_out);
}